// Round 9
// baseline (276.024 us; speedup 1.0000x reference)
//
#include <hip/hip_runtime.h>
#include <cmath>

typedef __bf16 bf16x8 __attribute__((ext_vector_type(8)));
typedef __bf16 bf16x4 __attribute__((ext_vector_type(4)));
typedef float f32x4 __attribute__((ext_vector_type(4)));
typedef short s16x4 __attribute__((ext_vector_type(4)));
typedef unsigned short u16;
typedef unsigned int u32;

__device__ __forceinline__ u16 f2bf(float f) {
  union { float f; unsigned int u; } v; v.f = f;
  unsigned int u = v.u;
  return (u16)((u + 0x7FFFu + ((u >> 16) & 1u)) >> 16);
}

__device__ __forceinline__ float bf2f(u16 b) {
  union { u32 u; float f; } v; v.u = (u32)b << 16; return v.f;
}

__device__ __forceinline__ float geluf(float x) {
  return 0.5f * x * (1.0f + erff(x * 0.7071067811865475f));
}

__device__ __forceinline__ void ld4bf(const u16* p, float* o) {
  uint2 w = *(const uint2*)p;
  o[0] = bf2f((u16)(w.x & 0xffff)); o[1] = bf2f((u16)(w.x >> 16));
  o[2] = bf2f((u16)(w.y & 0xffff)); o[3] = bf2f((u16)(w.y >> 16));
}

__device__ __forceinline__ void ld8bf(const u16* p, float* o) {
  uint4 w = *(const uint4*)p;
  o[0] = bf2f((u16)(w.x & 0xffff)); o[1] = bf2f((u16)(w.x >> 16));
  o[2] = bf2f((u16)(w.y & 0xffff)); o[3] = bf2f((u16)(w.y >> 16));
  o[4] = bf2f((u16)(w.z & 0xffff)); o[5] = bf2f((u16)(w.z >> 16));
  o[6] = bf2f((u16)(w.w & 0xffff)); o[7] = bf2f((u16)(w.w >> 16));
}

__device__ __forceinline__ uint4 pack8(const float* o) {
  uint4 r;
  r.x = (u32)f2bf(o[0]) | ((u32)f2bf(o[1]) << 16);
  r.y = (u32)f2bf(o[2]) | ((u32)f2bf(o[3]) << 16);
  r.z = (u32)f2bf(o[4]) | ((u32)f2bf(o[5]) << 16);
  r.w = (u32)f2bf(o[6]) | ((u32)f2bf(o[7]) << 16);
  return r;
}

// 16x16x16 bf16 MFMA (legacy shape; B-frag layout k=quad*4+j matches S^T C/D rows)
__device__ __forceinline__ f32x4 mfma_16x16x16_bf16(s16x4 a, s16x4 b, f32x4 c) {
#if __has_builtin(__builtin_amdgcn_mfma_f32_16x16x16bf16_1k)
  return __builtin_amdgcn_mfma_f32_16x16x16bf16_1k(a, b, c, 0, 0, 0);
#else
  f32x4 d;
  asm volatile("v_mfma_f32_16x16x16_bf16 %0, %1, %2, %3"
               : "=v"(d) : "v"(a), "v"(b), "0"(c));
  return d;
#endif
}

// async global->LDS, 16B per lane. LDS dest = wave-uniform base + lane*16.
__device__ __forceinline__ void gl_lds16(const void* g, void* l) {
  __builtin_amdgcn_global_load_lds(
      (const __attribute__((address_space(1))) u32*)g,
      (__attribute__((address_space(3))) u32*)l, 16, 0, 0);
}

// ------ fused: weight transposes + hidden f32->bf16 cvt, one launch ------
// blocks <2656: transpose 64x64 tiles as before; blocks >=2656: cvt 8 elems/thread.
__global__ __launch_bounds__(256) void transpose_all(const float* __restrict__ Wq,
                                                     const float* __restrict__ Wk,
                                                     const float* __restrict__ Wv,
                                                     const float* __restrict__ Wo,
                                                     const float* __restrict__ tWq,
                                                     const float* __restrict__ tWv,
                                                     u16* __restrict__ WqkvT,
                                                     u16* __restrict__ WoT,
                                                     u16* __restrict__ Tt,
                                                     const float* __restrict__ hidden,
                                                     u16* __restrict__ Xb) {
  int b = blockIdx.x;
  if (b >= 2656) {  // cvt path
    int i = (b - 2656) * 256 + threadIdx.x;
    const float4* p = (const float4*)hidden + 2 * (size_t)i;
    float4 a = p[0], c = p[1];
    uint4 o;
    o.x = (u32)f2bf(a.x) | ((u32)f2bf(a.y) << 16);
    o.y = (u32)f2bf(a.z) | ((u32)f2bf(a.w) << 16);
    o.z = (u32)f2bf(c.x) | ((u32)f2bf(c.y) << 16);
    o.w = (u32)f2bf(c.z) | ((u32)f2bf(c.w) << 16);
    ((uint4*)Xb)[i] = o;
    return;
  }
  __shared__ float tile[64][65];
  const float* in; u16* out; int R, C, bx, by;
  if (b < 1024)      { in = Wq;  out = WqkvT;                R = 2048; C = 2048; bx = b & 31; by = b >> 5; }
  else if (b < 1280) { b -= 1024; in = Wk; out = WqkvT + 2048ull * 2048; R = 2048; C = 512; bx = b & 7; by = b >> 3; }
  else if (b < 1536) { b -= 1280; in = Wv; out = WqkvT + 2560ull * 2048; R = 2048; C = 512; bx = b & 7; by = b >> 3; }
  else if (b < 2560) { b -= 1536; in = Wo; out = WoT;        R = 2048; C = 2048; bx = b & 31; by = b >> 5; }
  else if (b < 2608) { b -= 2560; in = tWq; out = Tt;               R = 3072; C = 32; bx = 0; by = b; }
  else               { b -= 2608; in = tWv; out = Tt + 32ull * 3072; R = 3072; C = 32; bx = 0; by = b; }

  const int t = threadIdx.x;
  const int r0 = by * 64, c0 = bx * 64;
  const int lr = t >> 4, lc4 = (t & 15) * 4;
#pragma unroll
  for (int p = 0; p < 4; ++p) {
    int r = p * 16 + lr;
    float4 v = {0.f, 0.f, 0.f, 0.f};
    if (c0 + lc4 < C) v = *(const float4*)(in + (size_t)(r0 + r) * C + c0 + lc4);
    tile[r][lc4] = v.x; tile[r][lc4 + 1] = v.y;
    tile[r][lc4 + 2] = v.z; tile[r][lc4 + 3] = v.w;
  }
  __syncthreads();
  const int cg = t >> 4, rr4 = (t & 15) * 4;
#pragma unroll
  for (int p = 0; p < 4; ++p) {
    int c = p * 16 + cg;
    if (c0 + c < C) {
      uint2 w;
      w.x = (u32)f2bf(tile[rr4][c])     | ((u32)f2bf(tile[rr4 + 1][c]) << 16);
      w.y = (u32)f2bf(tile[rr4 + 2][c]) | ((u32)f2bf(tile[rr4 + 3][c]) << 16);
      *(uint2*)(out + (size_t)(c0 + c) * R + r0 + rr4) = w;
    }
  }
}

// ---------------- bf16 MFMA GEMM: Cpart[z] = A(MxK) * Bt(NxK)^T over K-chunk z --------
// BF16OUT: stage C tile in LDS as bf16, then coalesced 16B/lane stores (halves
// split-K partial write traffic; reduce reads bf16).
template <int WR, int WC, bool BF16OUT>
__global__ __launch_bounds__(256, 3) void gemm_bt(const u16* __restrict__ A,
                                                  const u16* __restrict__ Bt,
                                                  void* __restrict__ Cpart,
                                                  int M, int N, int K, int kPer) {
  constexpr int BM = WR * 64, BN = WC * 64;
  __shared__ __attribute__((aligned(16))) u16 S[(BM + BN) * 64];
  u16* As = S;
  u16* Bs = S + BM * 64;
  const int tid = threadIdx.x, wid = tid >> 6, lane = tid & 63;
  const int l16 = lane & 15, quad = lane >> 4;
  const int wm = (wid % WR) * 64, wn = (wid / WR) * 64;
  const int m0 = blockIdx.y * BM, n0 = blockIdx.x * BN;
  const int kIters = K >> 6;
  const int kStart = blockIdx.z * kPer;
  const int kEnd = (kStart + kPer < kIters) ? (kStart + kPer) : kIters;

  const int lrow = lane >> 3;
  const int swz = (lane & 7) ^ lrow;
  const u16* gAb = A + (size_t)m0 * K + (size_t)swz * 8;
  const u16* gBb = Bt + (size_t)n0 * K + (size_t)swz * 8;
  const int sx = l16 & 7;

  f32x4 acc[4][4] = {};
  for (int kt = kStart; kt < kEnd; ++kt) {
    __syncthreads();
    const u16* gA = gAb + (size_t)kt * 64;
    const u16* gB = gBb + (size_t)kt * 64;
#pragma unroll
    for (int j = 0; j < BM / 32; ++j) {
      int i = wid * (BM / 32) + j;
      gl_lds16(gA + (size_t)(i * 8 + lrow) * K, &As[i * 512]);
    }
#pragma unroll
    for (int j = 0; j < BN / 32; ++j) {
      int i = wid * (BN / 32) + j;
      gl_lds16(gB + (size_t)(i * 8 + lrow) * K, &Bs[i * 512]);
    }
    __syncthreads();
    bf16x8 af[4][2], bfr[4][2];
#pragma unroll
    for (int mt = 0; mt < 4; ++mt)
#pragma unroll
      for (int ks = 0; ks < 2; ++ks)
        af[mt][ks] = *(const bf16x8*)(&As[(wm + mt * 16 + l16) * 64 +
                                          (((ks * 4 + quad) ^ sx) * 8)]);
#pragma unroll
    for (int nt = 0; nt < 4; ++nt)
#pragma unroll
      for (int ks = 0; ks < 2; ++ks)
        bfr[nt][ks] = *(const bf16x8*)(&Bs[(wn + nt * 16 + l16) * 64 +
                                           (((ks * 4 + quad) ^ sx) * 8)]);
#pragma unroll
    for (int mt = 0; mt < 4; ++mt)
#pragma unroll
      for (int nt = 0; nt < 4; ++nt)
#pragma unroll
        for (int ks = 0; ks < 2; ++ks)
          acc[mt][nt] = __builtin_amdgcn_mfma_f32_16x16x32_bf16(
              af[mt][ks], bfr[nt][ks], acc[mt][nt], 0, 0, 0);
  }

  if constexpr (BF16OUT) {
    // stage bf16 C tile in LDS, then coalesced 16B/lane global stores
    __syncthreads();
#pragma unroll
    for (int mt = 0; mt < 4; ++mt)
#pragma unroll
      for (int nt = 0; nt < 4; ++nt)
#pragma unroll
        for (int r = 0; r < 4; ++r)
          S[(wm + mt * 16 + quad * 4 + r) * BN + wn + nt * 16 + l16] =
              f2bf(acc[mt][nt][r]);
    __syncthreads();
    u16* Cp = (u16*)Cpart + (size_t)blockIdx.z * M * N;
#pragma unroll
    for (int it = 0; it < (BM * BN) / 2048; ++it) {
      int off = it * 2048 + tid * 8;
      int row = off / BN, col = off % BN;
      *(uint4*)(Cp + (size_t)(m0 + row) * N + n0 + col) = *(const uint4*)(S + off);
    }
  } else {
    float* C = (float*)Cpart + (size_t)blockIdx.z * M * N;
#pragma unroll
    for (int mt = 0; mt < 4; ++mt)
#pragma unroll
      for (int nt = 0; nt < 4; ++nt)
#pragma unroll
        for (int r = 0; r < 4; ++r) {
          int row = m0 + wm + mt * 16 + quad * 4 + r;
          int col = n0 + wn + nt * 16 + l16;
          C[(size_t)row * N + col] = acc[mt][nt][r];
        }
  }
}

// ---------------- reduce kernels (split-K epilogues) ----------------
// sum P bf16 partials (8/thread) -> bf16 sum (for prep) + bf16 gelu (feat)
__global__ __launch_bounds__(256) void reduce_gelu_b(const u16* __restrict__ base,
                                                     int P, int n8,
                                                     u16* __restrict__ qkvs,
                                                     u16* __restrict__ gout) {
  int i = blockIdx.x * 256 + threadIdx.x;
  if (i >= n8) return;
  size_t n = (size_t)n8 * 8;
  float s[8];
  uint4 v = ((const uint4*)base)[i];
  const u16* pv = (const u16*)&v;
#pragma unroll
  for (int j = 0; j < 8; ++j) s[j] = bf2f(pv[j]);
  for (int p = 1; p < P; ++p) {
    uint4 w = *(const uint4*)(base + (size_t)p * n + (size_t)i * 8);
    const u16* pw = (const u16*)&w;
#pragma unroll
    for (int j = 0; j < 8; ++j) s[j] += bf2f(pw[j]);
  }
  uint4 os, og;
  u16* ps = (u16*)&os;
  u16* pg = (u16*)&og;
#pragma unroll
  for (int j = 0; j < 8; ++j) {
    ps[j] = f2bf(s[j]);
    pg[j] = f2bf(geluf(s[j]));
  }
  ((uint4*)qkvs)[i] = os;
  ((uint4*)gout)[i] = og;
}

// sum P bf16 partials (8 elems/thread) -> f32 out
__global__ __launch_bounds__(256) void reduce_add_bf16(const u16* __restrict__ base,
                                                       int P, int n8,
                                                       float* __restrict__ dst) {
  int i = blockIdx.x * 256 + threadIdx.x;
  if (i >= n8) return;
  size_t n = (size_t)n8 * 8;
  float s[8];
  uint4 v = ((const uint4*)base)[i];
  const u16* pv = (const u16*)&v;
#pragma unroll
  for (int j = 0; j < 8; ++j) s[j] = bf2f(pv[j]);
  for (int p = 1; p < P; ++p) {
    uint4 w = *(const uint4*)(base + (size_t)p * n + (size_t)i * 8);
    const u16* pw = (const u16*)&w;
#pragma unroll
    for (int j = 0; j < 8; ++j) s[j] += bf2f(pw[j]);
  }
  float4 o0 = {s[0], s[1], s[2], s[3]}, o1 = {s[4], s[5], s[6], s[7]};
  ((float4*)dst)[2 * i] = o0;
  ((float4*)dst)[2 * i + 1] = o1;
}

__global__ __launch_bounds__(256) void reduce_tanh(const float* __restrict__ base, int P,
                                                   int n, float* __restrict__ tokq,
                                                   float* __restrict__ tokv) {
  int i = blockIdx.x * 256 + threadIdx.x;
  if (i >= n) return;
  float v = base[i];
  for (int p = 1; p < P; ++p) v += base[(size_t)p * n + i];
  float t = tanhf(v);
  int col = i & 63, row = i >> 6;
  if (col < 32) tokq[row * 32 + col] = t;
  else          tokv[row * 32 + (col - 32)] = t;
}

// ---------------- prep: tau scaling + RoPE + layouts for attention ----------------
// qkvs is the bf16 qkv sum. Q pre-scaled by 0.125*log2(e) for exp2-domain softmax.
// Vectorized: 8 outputs/thread-unit; rot half = two 8B loads, pass half = one 16B load.
#define QSCALE 0.18033688011112042f
__global__ __launch_bounds__(256) void prep_qkv(const u16* __restrict__ qkvs,
                                                const float* __restrict__ tokq,
                                                const float* __restrict__ tokv,
                                                const float* __restrict__ alpha,
                                                const float* __restrict__ cosb,
                                                const float* __restrict__ sinb,
                                                const int* __restrict__ pos_ids,
                                                u16* __restrict__ Qb,
                                                u16* __restrict__ Kb,
                                                u16* __restrict__ Vt,
                                                u16* __restrict__ Vb) {
  const int s = blockIdx.x;
  const int tid = threadIdx.x;
  __shared__ float cs[16], sn[16], tq_s[32], tv_s[32];
  if (tid < 16) { cs[tid] = cosb[s * 16 + tid]; sn[tid] = sinb[s * 16 + tid]; }
  if (tid < 32) {
    float p = (float)pos_ids[s] + 1.0f;
    float sig = 1.0f / (1.0f + __expf(-alpha[tid] * logf(p)));
    float taupos = 0.5f + sig;
    tq_s[tid] = (tokq[s * 32 + tid] + taupos) * QSCALE;
    tv_s[tid] = tokv[s * 32 + tid] + taupos;
  }
  __syncthreads();
  const u16* row = qkvs + (size_t)s * 3072;

  if (Vb) {  // vectorized path (big ws): 384 8-wide units over 256 threads
    for (int u = tid; u < 384; u += 256) {
      if (u < 256) {  // Q: h = u>>3, dblk = u&7
        int h = u >> 3, dblk = u & 7;
        float tq = tq_s[h];
        float o[8];
        if (dblk < 4) {
          int i0 = dblk * 4;
          float xr[4], xi[4];
          ld4bf(row + h * 64 + i0, xr);
          ld4bf(row + h * 64 + 16 + i0, xi);
#pragma unroll
          for (int j = 0; j < 4; ++j) {
            float a = xr[j] * tq, b = xi[j] * tq;
            o[2 * j]     = a * cs[i0 + j] - b * sn[i0 + j];
            o[2 * j + 1] = a * sn[i0 + j] + b * cs[i0 + j];
          }
        } else {
          float x[8];
          ld8bf(row + h * 64 + dblk * 8, x);
#pragma unroll
          for (int j = 0; j < 8; ++j) o[j] = x[j] * tq;
        }
        *(uint4*)(Qb + ((size_t)h * 2048 + s) * 64 + dblk * 8) = pack8(o);
      } else if (u < 320) {  // K
        int u2 = u - 256;
        int h = u2 >> 3, dblk = u2 & 7;
        const u16* kr = row + 2048;
        float o[8];
        if (dblk < 4) {
          int i0 = dblk * 4;
          float xr[4], xi[4];
          ld4bf(kr + h * 64 + i0, xr);
          ld4bf(kr + h * 64 + 16 + i0, xi);
#pragma unroll
          for (int j = 0; j < 4; ++j) {
            o[2 * j]     = xr[j] * cs[i0 + j] - xi[j] * sn[i0 + j];
            o[2 * j + 1] = xr[j] * sn[i0 + j] + xi[j] * cs[i0 + j];
          }
        } else {
          float x[8];
          ld8bf(kr + h * 64 + dblk * 8, x);
#pragma unroll
          for (int j = 0; j < 8; ++j) o[j] = x[j];
        }
        *(uint4*)(Kb + ((size_t)h * 2048 + s) * 64 + dblk * 8) = pack8(o);
      } else {  // V -> Vb (vtrans handles Vt)
        int u2 = u - 320;
        int h = u2 >> 3, dblk = u2 & 7;
        float tv = tv_s[h];
        float x[8], o[8];
        ld8bf(row + 2560 + h * 64 + dblk * 8, x);
#pragma unroll
        for (int j = 0; j < 8; ++j) o[j] = x[j] * tv;
        *(uint4*)(Vb + ((size_t)h * 2048 + s) * 64 + dblk * 8) = pack8(o);
      }
    }
    return;
  }

  // scalar fallback (small ws): writes Vt directly
  for (int idx = tid; idx < 2048; idx += 256) {
    int h = idx >> 6, d = idx & 63;
    float tq = tq_s[h];
    float v;
    if (d < 32) {
      int i = d >> 1;
      float xr = bf2f(row[h * 64 + i]) * tq, xi = bf2f(row[h * 64 + 16 + i]) * tq;
      v = (d & 1) ? (xr * sn[i] + xi * cs[i]) : (xr * cs[i] - xi * sn[i]);
    } else v = bf2f(row[h * 64 + d]) * tq;
    Qb[((size_t)h * 2048 + s) * 64 + d] = f2bf(v);
  }
  for (int idx = tid; idx < 512; idx += 256) {
    int h = idx >> 6, d = idx & 63;
    const u16* kr = row + 2048;
    float v;
    if (d < 32) {
      int i = d >> 1;
      float xr = bf2f(kr[h * 64 + i]), xi = bf2f(kr[h * 64 + 16 + i]);
      v = (d & 1) ? (xr * sn[i] + xi * cs[i]) : (xr * cs[i] - xi * sn[i]);
    } else v = bf2f(kr[h * 64 + d]);
    Kb[((size_t)h * 2048 + s) * 64 + d] = f2bf(v);
  }
  for (int idx = tid; idx < 512; idx += 256) {
    int h = idx >> 6, d = idx & 63;
    float v = bf2f(row[2560 + h * 64 + d]) * tv_s[h];
    Vt[((size_t)h * 64 + d) * 2048 + s] = f2bf(v);
  }
}

// ---------------- bf16 transpose Vb[h][s][d] -> Vt[h][d][s] ----------------
__global__ __launch_bounds__(256) void vtrans(const u16* __restrict__ Vb,
                                              u16* __restrict__ Vt) {
  __shared__ u16 t[64][68];
  const int s0 = blockIdx.x * 64, h = blockIdx.y;
  const int tid = threadIdx.x;
  const u16* src = Vb + ((size_t)h * 2048 + s0) * 64;
#pragma unroll
  for (int p = 0; p < 4; ++p) {
    int v = p * 256 + tid;
    int r = v >> 4, c = (v & 15) * 4;
    uint2 w = *(const uint2*)(src + (size_t)r * 64 + c);
    t[r][c] = (u16)(w.x & 0xffff); t[r][c + 1] = (u16)(w.x >> 16);
    t[r][c + 2] = (u16)(w.y & 0xffff); t[r][c + 3] = (u16)(w.y >> 16);
  }
  __syncthreads();
  u16* dst = Vt + (size_t)h * 64 * 2048 + s0;
#pragma unroll
  for (int p = 0; p < 4; ++p) {
    int v = p * 256 + tid;
    int d = v >> 4, s = (v & 15) * 4;
    uint2 w;
    w.x = (u32)t[s][d] | ((u32)t[s + 1][d] << 16);
    w.y = (u32)t[s + 2][d] | ((u32)t[s + 3][d] << 16);
    *(uint2*)(dst + (size_t)d * 2048 + s) = w;
  }
}

// ---------------- flash attention (r5/v10 body: best-measured 43.2us) ----------------
// Double-buffered, one __syncthreads per tile, 16x16x16 PV with in-lane P frags,
// XCD pinning (all 51 chunks of a head share bid%8), LDS-staged coalesced epilogue.
__global__ __launch_bounds__(256, 4) void flash_attn(const u16* __restrict__ Qb,
                                                     const u16* __restrict__ Kb,
                                                     const u16* __restrict__ Vt,
                                                     u16* __restrict__ Opart,
                                                     float* __restrict__ ml) {
  __shared__ __attribute__((aligned(16))) u16 KsB[2][4096];
  __shared__ __attribute__((aligned(16))) u16 VsB[2][4096];
  const int bid = blockIdx.x;
  const int h = (bid & 7) | (((bid >> 3) & 3) << 3);  // head: bid%8 fixed per head -> one XCD
  const int e = 50 - (bid >> 5);                      // reversed: heaviest (qb=15) first
  const int kvh = h >> 2;
  // decode e -> (qb, cc): group a (a=0..5) holds qb=3a..3a+2, each with a+1 chunks of 6
  int a = 0;
  while (3 * (a + 1) * (a + 2) / 2 <= e) ++a;
  const int rem = e - 3 * a * (a + 1) / 2;
  const int qb = 3 * a + rem / (a + 1);
  const int cc = rem % (a + 1);
  const int k0 = cc * 6;
  const int kvTend = 2 * qb + 2;
  const int k1 = (k0 + 6 < kvTend) ? (k0 + 6) : kvTend;
  const int pid = h * 51 + e;

  const int tid = threadIdx.x, wid = tid >> 6, lane = tid & 63;
  const int l16 = lane & 15, quad = lane >> 4;
  const int lrow = lane >> 3, swz = (lane & 7) ^ lrow, sx = l16 & 7;

  const int q0 = qb * 128 + wid * 32;
  bf16x8 qf[2][2];
#pragma unroll
  for (int mt = 0; mt < 2; ++mt)
#pragma unroll
    for (int ks = 0; ks < 2; ++ks)
      qf[mt][ks] = *(const bf16x8*)(Qb + ((size_t)h * 2048 + q0 + mt * 16 + l16) * 64 +
                                    ks * 32 + quad * 8);

  f32x4 oacc[2][4] = {};          // O^T frags: [q-half][d-frag], lane q = l16
  float mrun[2] = {-3e38f, -3e38f};
  float lrun[2] = {0.f, 0.f};     // per-lane partial (reduced in epilogue)

  const u16* kgb = Kb + ((size_t)kvh * 2048) * 64;
  const u16* vgb = Vt + (size_t)kvh * 64 * 2048;

#define FA_STAGE(KT, BUF)                                                         \
  {                                                                               \
    const u16* kg_ = kgb + (size_t)(KT)*64 * 64;                                  \
    const u16* vg_ = vgb + (size_t)(KT)*64;                                       \
    _Pragma("unroll") for (int j = 0; j < 2; ++j) {                               \
      int i_ = wid * 2 + j;                                                       \
      gl_lds16(kg_ + (size_t)(i_ * 8 + lrow) * 64 + swz * 8, &KsB[BUF][i_ * 512]);\
      gl_lds16(vg_ + (size_t)(i_ * 8 + lrow) * 2048 + swz * 8, &VsB[BUF][i_ * 512]);\
    }                                                                             \
  }

  FA_STAGE(k0, 0)
  for (int kt = k0; kt < k1; ++kt) {
    const int cur = (kt - k0) & 1;
    __syncthreads();
    if (kt + 1 < k1) FA_STAGE(kt + 1, cur ^ 1)
    const u16* Ks = KsB[cur];
    const u16* Vs = VsB[cur];

    // S^T = K Q^T : sacc[mt][kf], C row = k (quad*4+r+16kf), col = q (l16)
    f32x4 sacc[2][4] = {};
    __builtin_amdgcn_s_setprio(1);
#pragma unroll
    for (int kf = 0; kf < 4; ++kf) {
      bf16x8 a0 = *(const bf16x8*)(Ks + (kf * 16 + l16) * 64 + ((quad ^ sx) << 3));
      bf16x8 a1 = *(const bf16x8*)(Ks + (kf * 16 + l16) * 64 + (((4 + quad) ^ sx) << 3));
      sacc[0][kf] = __builtin_amdgcn_mfma_f32_16x16x32_bf16(a0, qf[0][0], sacc[0][kf], 0, 0, 0);
      sacc[0][kf] = __builtin_amdgcn_mfma_f32_16x16x32_bf16(a1, qf[0][1], sacc[0][kf], 0, 0, 0);
      sacc[1][kf] = __builtin_amdgcn_mfma_f32_16x16x32_bf16(a0, qf[1][0], sacc[1][kf], 0, 0, 0);
      sacc[1][kf] = __builtin_amdgcn_mfma_f32_16x16x32_bf16(a1, qf[1][1], sacc[1][kf], 0, 0, 0);
    }
    __builtin_amdgcn_s_setprio(0);

    const bool msk = (kt >= 2 * qb);  // diagonal tiles only
    s16x4 pb[2][4];                   // PV B-frags, built in-lane (no redistribution)
#pragma unroll
    for (int mt = 0; mt < 2; ++mt) {
      const int qg = q0 + mt * 16 + l16;       // this lane's q (fixed)
      if (msk) {
        const int kb = kt * 64 + quad * 4;
#pragma unroll
        for (int kf = 0; kf < 4; ++kf)
#pragma unroll
          for (int r = 0; r < 4; ++r)
            if (kb + kf * 16 + r > qg) sacc[mt][kf][r] = -1e9f;
      }
      f32x4 m4 = sacc[mt][0];
      m4 = __builtin_elementwise_max(m4, sacc[mt][1]);
      m4 = __builtin_elementwise_max(m4, sacc[mt][2]);
      m4 = __builtin_elementwise_max(m4, sacc[mt][3]);
      float mx = fmaxf(fmaxf(m4[0], m4[1]), fmaxf(m4[2], m4[3]));
      mx = fmaxf(mx, __shfl_xor(mx, 16));
      mx = fmaxf(mx, __shfl_xor(mx, 32));
      float mn = fmaxf(mrun[mt], mx);
      float al = __builtin_amdgcn_exp2f(mrun[mt] - mn);
      mrun[mt] = mn;
      float psl = 0.f;
#pragma unroll
      for (int kf = 0; kf < 4; ++kf) {
        bf16x4 ph;
#pragma unroll
        for (int r = 0; r < 4; ++r) {
          float p = __builtin_amdgcn_exp2f(sacc[mt][kf][r] - mn);
          psl += p;
          ph[r] = (__bf16)p;
        }
        union { bf16x4 h; s16x4 s; } cv;
        cv.h = ph;
        pb[mt][kf] = cv.s;
      }
      lrun[mt] = lrun[mt] * al + psl;
#pragma unroll
      for (int df = 0; df < 4; ++df) oacc[mt][df] *= al;
    }

    // O^T += V^T P : A = Vs[d][k] (b64 frags), B = in-lane P frags (16x16x16)
    __builtin_amdgcn_s_setprio(1);
#pragma unroll
    for (int kf = 0; kf < 4; ++kf) {
#pragma unroll
      for (int df = 0; df < 4; ++df) {
        s16x4 va = *(const s16x4*)(Vs + (df * 16 + l16) * 64 +
                                   (((kf * 2 + (quad >> 1)) ^ sx) << 3) + ((quad & 1) << 2));
        oacc[0][df] = mfma_16x16x16_bf16(va, pb[0][kf], oacc[0][df]);
        oacc[1][df] = mfma_16x16x16_bf16(va, pb[1][kf], oacc[1][df]);
      }
    }
    __builtin_amdgcn_s_setprio(0);
  }
#undef FA_STAGE

  // epilogue: reduce lrun; stage bf16 O in LDS (XOR-swizzled 16B granules), then
  // fully-coalesced 16B/lane global writes. KsB (16KB) exactly holds 128x64 bf16.
  __syncthreads();                     // all waves done reading KsB
  char* Ls = (char*)KsB;
#pragma unroll
  for (int mt = 0; mt < 2; ++mt) {
    float lt = lrun[mt];
    lt += __shfl_xor(lt, 16);
    lt += __shfl_xor(lt, 32);
    const int qrow = wid * 32 + mt * 16 + l16;
#pragma unroll
    for (int df = 0; df < 4; ++df) {
      uint2 pk2;
      pk2.x = (u32)f2bf(oacc[mt][df][0]) | ((u32)f2bf(oacc[mt][df][1]) << 16);
      pk2.y = (u32)f2bf(oacc[mt][df][2]) | ((u32)f2bf(oacc[mt][df][3]) << 16);
      int boff = qrow * 128 + ((df * 32 + quad * 8) ^ ((qrow & 7) << 4));
      *(uint2*)(Ls + boff) = pk2;
    }
    if (quad == 0) {
      ml[((size_t)pid * 128 + qrow) * 2] = mrun[mt];
      ml[((size_t)pid * 128 + qrow) * 2 + 1] = lt;
    }
  }
  __syncthreads();
  char* Op = (char*)(Opart + (size_t)pid * 128 * 64);
#pragma unroll
  for (int p = 0; p < 4; ++p) {
    int off = p * 4096 + tid * 16;
    int row = off >> 7, wb = off & 127;
    uint4 v = *(const uint4*)(Ls + row * 128 + (wb ^ ((row & 7) << 4)));
    *(uint4*)(Op + off) = v;
  }
}

// ---------------- combine partials: O = sum(w_c O_c) / sum(w_c l_c) ----------------
__global__ __launch_bounds__(256) void fa_combine(const u16* __restrict__ Opart,
                                                  const float* __restrict__ ml,
                                                  u16* __restrict__ Ob) {
  const int qb = blockIdx.x, h = blockIdx.y;
  const int C = (2 * qb + 7) / 6;                  // chunks for this qb (size-6 chunks)
  const int aa = qb / 3, bb = qb % 3;
  const int base = h * 51 + 3 * aa * (aa + 1) / 2 + bb * (aa + 1);
  const int t = threadIdx.x;
#pragma unroll
  for (int u = 0; u < 8; ++u) {
    int unit = u * 256 + t;
    int row = unit >> 4, d4 = unit & 15;
    float mstar = -3e38f;
    for (int c = 0; c < C; ++c)
      mstar = fmaxf(mstar, ml[((size_t)(base + c) * 128 + row) * 2]);
    float4 o = {0.f, 0.f, 0.f, 0.f};
    float lsum = 0.f;
    for (int c = 0; c < C; ++c) {
      const float* mlp = &ml[((size_t)(base + c) * 128 + row) * 2];
      float w = __builtin_amdgcn_exp2f(mlp[0] - mstar);
      uint2 v = *(const uint2*)(Opart + ((size_t)(base + c) * 128 + row) * 64 + d4 * 4);
      o.x += w * bf2f((u16)(v.x & 0xffff));
      o.y += w * bf2f((u16)(v.x >> 16));
      o.z += w * bf2f((u16)(v.y & 0xffff));
      o.w += w * bf2f((u16)(v.y >> 16));
      lsum += w * mlp[1];
    }
    float inv = 1.0f / lsum;
    uint2 pk;
    pk.x = (u32)f2bf(o.x * inv) | ((u32)f2bf(o.y * inv) << 16);
    pk.y = (u32)f2bf(o.z * inv) | ((u32)f2bf(o.w * inv) << 16);
    *(uint2*)(Ob + (size_t)(qb * 128 + row) * 2048 + h * 64 + d4 * 4) = pk;
  }
}

// ---------------- launcher ----------------
extern "C" void kernel_launch(void* const* d_in, const int* in_sizes, int n_in,
                              void* d_out, int out_size, void* d_ws, size_t ws_size,
                              hipStream_t stream) {
  (void)in_sizes; (void)n_in; (void)out_size;
  const float* hidden = (const float*)d_in[0];
  const float* cosb   = (const float*)d_in[1];
  const float* sinb   = (const float*)d_in[2];
  const int*   pos    = (const int*)d_in[3];
  const float* Wq     = (const float*)d_in[4];
  const float* Wk     = (const float*)d_in[5];
  const float* Wv     = (const float*)d_in[6];
  const float* Wo     = (const float*)d_in[7];
  const float* tWq    = (const float*)d_in[8];
  const float* tWv    = (const float*)d_in[9];
  const float* alpha  = (const float*)d_in[10];
  float* out = (float*)d_out;

  const bool big = ws_size >= (size_t)120 * 1024 * 1024;
  const int Pq = big ? 2 : 1;
  const int Pt = big ? 8 : 1;
  const int Po = big ? 2 : 1;

  char* ws = (char*)d_ws;
  size_t off = 0;
  auto alloc = [&](size_t bytes) -> void* {
    void* p = ws + off;
    off += (bytes + 255) & ~(size_t)255;
    return p;
  };
  u16*   WoT   = (u16*)alloc(2048ull * 2048 * 2);
  u16*   Tt    = (u16*)alloc(64ull * 3072 * 2);
  u16*   Qb    = (u16*)alloc(32ull * 2048 * 64 * 2);
  u16*   Kb    = (u16*)alloc(8ull * 2048 * 64 * 2);
  u16*   Vt    = (u16*)alloc(8ull * 64 * 2048 * 2);
  u16*   Ob    = (u16*)alloc(2048ull * 2048 * 2);
  u16*   featb = (u16*)alloc(2048ull * 3072 * 2);
  float* tokq  = (float*)alloc(2048ull * 32 * 4);
  float* tokv  = (float*)alloc(2048ull * 32 * 4);
  u16*   Vb    = big ? (u16*)alloc(8ull * 2048 * 64 * 2) : nullptr;
  // early region (dead after prep) -> reused for flash partials -> out partials
  size_t E = off;
  u16*   Xb       = (u16*)alloc(2048ull * 2048 * 2);
  u16*   WqkvT    = (u16*)alloc(3072ull * 2048 * 2);
  u16*   qkvPartB = (u16*)alloc((size_t)Pq * 2048 * 3072 * 2);
  u16*   qkvs     = (u16*)alloc(2048ull * 3072 * 2);
  float* tokPart = (float*)(ws + E);
  u16*   Opart   = (u16*)(ws + E);                             // 1632*128*64*2 = 26.7 MB
  float* mlbuf   = (float*)(ws + E + 1632ull * 128 * 64 * 2);  // +1.7 MB
  u16*   outPart = (u16*)(ws + E);                             // Po*2048*2048*2 = 16.8 MB

  transpose_all<<<4704, 256, 0, stream>>>(Wq, Wk, Wv, Wo, tWq, tWv, WqkvT, WoT, Tt,
                                          hidden, Xb);

  gemm_bt<2, 2, true><<<dim3(24, 16, Pq), 256, 0, stream>>>(
      Xb, WqkvT, qkvPartB, 2048, 3072, 2048, (32 + Pq - 1) / Pq);
  reduce_gelu_b<<<3072, 256, 0, stream>>>(qkvPartB, Pq, 2048 * 3072 / 8, qkvs, featb);

  gemm_bt<4, 1, false><<<dim3(1, 8, Pt), 256, 0, stream>>>(
      featb, Tt, tokPart, 2048, 64, 3072, (48 + Pt - 1) / Pt);
  reduce_tanh<<<512, 256, 0, stream>>>(tokPart, Pt, 2048 * 64, tokq, tokv);

  prep_qkv<<<2048, 256, 0, stream>>>(qkvs, tokq, tokv, alpha, cosb, sinb, pos,
                                     Qb, Kb, Vt, Vb);
  if (big) vtrans<<<dim3(32, 8), 256, 0, stream>>>(Vb, Vt);

  flash_attn<<<1632, 256, 0, stream>>>(Qb, Kb, Vt, Opart, mlbuf);
  fa_combine<<<dim3(16, 32), 256, 0, stream>>>(Opart, mlbuf, Ob);

  gemm_bt<2, 2, true><<<dim3(16, 16, Po), 256, 0, stream>>>(
      Ob, WoT, outPart, 2048, 2048, 2048, (32 + Po - 1) / Po);
  reduce_add_bf16<<<2048, 256, 0, stream>>>(outPart, Po, 2048 * 2048 / 8, out);
}

// Round 11
// 273.685 us; speedup vs baseline: 1.0085x; 1.0085x over previous
//
#include <hip/hip_runtime.h>
#include <cmath>

typedef __bf16 bf16x8 __attribute__((ext_vector_type(8)));
typedef __bf16 bf16x4 __attribute__((ext_vector_type(4)));
typedef float f32x4 __attribute__((ext_vector_type(4)));
typedef short s16x4 __attribute__((ext_vector_type(4)));
typedef unsigned short u16;
typedef unsigned int u32;

__device__ __forceinline__ u16 f2bf(float f) {
  union { float f; unsigned int u; } v; v.f = f;
  unsigned int u = v.u;
  return (u16)((u + 0x7FFFu + ((u >> 16) & 1u)) >> 16);
}

__device__ __forceinline__ float bf2f(u16 b) {
  union { u32 u; float f; } v; v.u = (u32)b << 16; return v.f;
}

__device__ __forceinline__ float geluf(float x) {
  return 0.5f * x * (1.0f + erff(x * 0.7071067811865475f));
}

__device__ __forceinline__ void ld4bf(const u16* p, float* o) {
  uint2 w = *(const uint2*)p;
  o[0] = bf2f((u16)(w.x & 0xffff)); o[1] = bf2f((u16)(w.x >> 16));
  o[2] = bf2f((u16)(w.y & 0xffff)); o[3] = bf2f((u16)(w.y >> 16));
}

__device__ __forceinline__ void ld8bf(const u16* p, float* o) {
  uint4 w = *(const uint4*)p;
  o[0] = bf2f((u16)(w.x & 0xffff)); o[1] = bf2f((u16)(w.x >> 16));
  o[2] = bf2f((u16)(w.y & 0xffff)); o[3] = bf2f((u16)(w.y >> 16));
  o[4] = bf2f((u16)(w.z & 0xffff)); o[5] = bf2f((u16)(w.z >> 16));
  o[6] = bf2f((u16)(w.w & 0xffff)); o[7] = bf2f((u16)(w.w >> 16));
}

__device__ __forceinline__ uint4 pack8(const float* o) {
  uint4 r;
  r.x = (u32)f2bf(o[0]) | ((u32)f2bf(o[1]) << 16);
  r.y = (u32)f2bf(o[2]) | ((u32)f2bf(o[3]) << 16);
  r.z = (u32)f2bf(o[4]) | ((u32)f2bf(o[5]) << 16);
  r.w = (u32)f2bf(o[6]) | ((u32)f2bf(o[7]) << 16);
  return r;
}

// 16x16x16 bf16 MFMA (legacy shape; B-frag layout k=quad*4+j matches S^T C/D rows)
__device__ __forceinline__ f32x4 mfma_16x16x16_bf16(s16x4 a, s16x4 b, f32x4 c) {
#if __has_builtin(__builtin_amdgcn_mfma_f32_16x16x16bf16_1k)
  return __builtin_amdgcn_mfma_f32_16x16x16bf16_1k(a, b, c, 0, 0, 0);
#else
  f32x4 d;
  asm volatile("v_mfma_f32_16x16x16_bf16 %0, %1, %2, %3"
               : "=v"(d) : "v"(a), "v"(b), "0"(c));
  return d;
#endif
}

// async global->LDS, 16B per lane. LDS dest = wave-uniform base + lane*16.
__device__ __forceinline__ void gl_lds16(const void* g, void* l) {
  __builtin_amdgcn_global_load_lds(
      (const __attribute__((address_space(1))) u32*)g,
      (__attribute__((address_space(3))) u32*)l, 16, 0, 0);
}

// ------ fused: weight transposes + hidden f32->bf16 cvt, one launch ------
// blocks <2656: transpose 64x64 tiles as before; blocks >=2656: cvt 8 elems/thread.
__global__ __launch_bounds__(256) void transpose_all(const float* __restrict__ Wq,
                                                     const float* __restrict__ Wk,
                                                     const float* __restrict__ Wv,
                                                     const float* __restrict__ Wo,
                                                     const float* __restrict__ tWq,
                                                     const float* __restrict__ tWv,
                                                     u16* __restrict__ WqkvT,
                                                     u16* __restrict__ WoT,
                                                     u16* __restrict__ Tt,
                                                     const float* __restrict__ hidden,
                                                     u16* __restrict__ Xb) {
  int b = blockIdx.x;
  if (b >= 2656) {  // cvt path
    int i = (b - 2656) * 256 + threadIdx.x;
    const float4* p = (const float4*)hidden + 2 * (size_t)i;
    float4 a = p[0], c = p[1];
    uint4 o;
    o.x = (u32)f2bf(a.x) | ((u32)f2bf(a.y) << 16);
    o.y = (u32)f2bf(a.z) | ((u32)f2bf(a.w) << 16);
    o.z = (u32)f2bf(c.x) | ((u32)f2bf(c.y) << 16);
    o.w = (u32)f2bf(c.z) | ((u32)f2bf(c.w) << 16);
    ((uint4*)Xb)[i] = o;
    return;
  }
  __shared__ float tile[64][65];
  const float* in; u16* out; int R, C, bx, by;
  if (b < 1024)      { in = Wq;  out = WqkvT;                R = 2048; C = 2048; bx = b & 31; by = b >> 5; }
  else if (b < 1280) { b -= 1024; in = Wk; out = WqkvT + 2048ull * 2048; R = 2048; C = 512; bx = b & 7; by = b >> 3; }
  else if (b < 1536) { b -= 1280; in = Wv; out = WqkvT + 2560ull * 2048; R = 2048; C = 512; bx = b & 7; by = b >> 3; }
  else if (b < 2560) { b -= 1536; in = Wo; out = WoT;        R = 2048; C = 2048; bx = b & 31; by = b >> 5; }
  else if (b < 2608) { b -= 2560; in = tWq; out = Tt;               R = 3072; C = 32; bx = 0; by = b; }
  else               { b -= 2608; in = tWv; out = Tt + 32ull * 3072; R = 3072; C = 32; bx = 0; by = b; }

  const int t = threadIdx.x;
  const int r0 = by * 64, c0 = bx * 64;
  const int lr = t >> 4, lc4 = (t & 15) * 4;
#pragma unroll
  for (int p = 0; p < 4; ++p) {
    int r = p * 16 + lr;
    float4 v = {0.f, 0.f, 0.f, 0.f};
    if (c0 + lc4 < C) v = *(const float4*)(in + (size_t)(r0 + r) * C + c0 + lc4);
    tile[r][lc4] = v.x; tile[r][lc4 + 1] = v.y;
    tile[r][lc4 + 2] = v.z; tile[r][lc4 + 3] = v.w;
  }
  __syncthreads();
  const int cg = t >> 4, rr4 = (t & 15) * 4;
#pragma unroll
  for (int p = 0; p < 4; ++p) {
    int c = p * 16 + cg;
    if (c0 + c < C) {
      uint2 w;
      w.x = (u32)f2bf(tile[rr4][c])     | ((u32)f2bf(tile[rr4 + 1][c]) << 16);
      w.y = (u32)f2bf(tile[rr4 + 2][c]) | ((u32)f2bf(tile[rr4 + 3][c]) << 16);
      *(uint2*)(out + (size_t)(c0 + c) * R + r0 + rr4) = w;
    }
  }
}

// ---------------- bf16 MFMA GEMM: Cpart[z] = A(MxK) * Bt(NxK)^T over K-chunk z --------
// BF16OUT: stage C tile in LDS as bf16, then coalesced 16B/lane stores (halves
// split-K partial write traffic; reduce reads bf16).
template <int WR, int WC, bool BF16OUT>
__global__ __launch_bounds__(256, 3) void gemm_bt(const u16* __restrict__ A,
                                                  const u16* __restrict__ Bt,
                                                  void* __restrict__ Cpart,
                                                  int M, int N, int K, int kPer) {
  constexpr int BM = WR * 64, BN = WC * 64;
  __shared__ __attribute__((aligned(16))) u16 S[(BM + BN) * 64];
  u16* As = S;
  u16* Bs = S + BM * 64;
  const int tid = threadIdx.x, wid = tid >> 6, lane = tid & 63;
  const int l16 = lane & 15, quad = lane >> 4;
  const int wm = (wid % WR) * 64, wn = (wid / WR) * 64;
  const int m0 = blockIdx.y * BM, n0 = blockIdx.x * BN;
  const int kIters = K >> 6;
  const int kStart = blockIdx.z * kPer;
  const int kEnd = (kStart + kPer < kIters) ? (kStart + kPer) : kIters;

  const int lrow = lane >> 3;
  const int swz = (lane & 7) ^ lrow;
  const u16* gAb = A + (size_t)m0 * K + (size_t)swz * 8;
  const u16* gBb = Bt + (size_t)n0 * K + (size_t)swz * 8;
  const int sx = l16 & 7;

  f32x4 acc[4][4] = {};
  for (int kt = kStart; kt < kEnd; ++kt) {
    __syncthreads();
    const u16* gA = gAb + (size_t)kt * 64;
    const u16* gB = gBb + (size_t)kt * 64;
#pragma unroll
    for (int j = 0; j < BM / 32; ++j) {
      int i = wid * (BM / 32) + j;
      gl_lds16(gA + (size_t)(i * 8 + lrow) * K, &As[i * 512]);
    }
#pragma unroll
    for (int j = 0; j < BN / 32; ++j) {
      int i = wid * (BN / 32) + j;
      gl_lds16(gB + (size_t)(i * 8 + lrow) * K, &Bs[i * 512]);
    }
    __syncthreads();
    bf16x8 af[4][2], bfr[4][2];
#pragma unroll
    for (int mt = 0; mt < 4; ++mt)
#pragma unroll
      for (int ks = 0; ks < 2; ++ks)
        af[mt][ks] = *(const bf16x8*)(&As[(wm + mt * 16 + l16) * 64 +
                                          (((ks * 4 + quad) ^ sx) * 8)]);
#pragma unroll
    for (int nt = 0; nt < 4; ++nt)
#pragma unroll
      for (int ks = 0; ks < 2; ++ks)
        bfr[nt][ks] = *(const bf16x8*)(&Bs[(wn + nt * 16 + l16) * 64 +
                                           (((ks * 4 + quad) ^ sx) * 8)]);
#pragma unroll
    for (int mt = 0; mt < 4; ++mt)
#pragma unroll
      for (int nt = 0; nt < 4; ++nt)
#pragma unroll
        for (int ks = 0; ks < 2; ++ks)
          acc[mt][nt] = __builtin_amdgcn_mfma_f32_16x16x32_bf16(
              af[mt][ks], bfr[nt][ks], acc[mt][nt], 0, 0, 0);
  }

  if constexpr (BF16OUT) {
    // stage bf16 C tile in LDS, then coalesced 16B/lane global stores
    __syncthreads();
#pragma unroll
    for (int mt = 0; mt < 4; ++mt)
#pragma unroll
      for (int nt = 0; nt < 4; ++nt)
#pragma unroll
        for (int r = 0; r < 4; ++r)
          S[(wm + mt * 16 + quad * 4 + r) * BN + wn + nt * 16 + l16] =
              f2bf(acc[mt][nt][r]);
    __syncthreads();
    u16* Cp = (u16*)Cpart + (size_t)blockIdx.z * M * N;
#pragma unroll
    for (int it = 0; it < (BM * BN) / 2048; ++it) {
      int off = it * 2048 + tid * 8;
      int row = off / BN, col = off % BN;
      *(uint4*)(Cp + (size_t)(m0 + row) * N + n0 + col) = *(const uint4*)(S + off);
    }
  } else {
    float* C = (float*)Cpart + (size_t)blockIdx.z * M * N;
#pragma unroll
    for (int mt = 0; mt < 4; ++mt)
#pragma unroll
      for (int nt = 0; nt < 4; ++nt)
#pragma unroll
        for (int r = 0; r < 4; ++r) {
          int row = m0 + wm + mt * 16 + quad * 4 + r;
          int col = n0 + wn + nt * 16 + l16;
          C[(size_t)row * N + col] = acc[mt][nt][r];
        }
  }
}

// ---------------- reduce kernels (split-K epilogues) ----------------
// sum P bf16 partials (8/thread) -> bf16 sum (for prep) + bf16 gelu (feat)
__global__ __launch_bounds__(256) void reduce_gelu_b(const u16* __restrict__ base,
                                                     int P, int n8,
                                                     u16* __restrict__ qkvs,
                                                     u16* __restrict__ gout) {
  int i = blockIdx.x * 256 + threadIdx.x;
  if (i >= n8) return;
  size_t n = (size_t)n8 * 8;
  float s[8];
  uint4 v = ((const uint4*)base)[i];
  const u16* pv = (const u16*)&v;
#pragma unroll
  for (int j = 0; j < 8; ++j) s[j] = bf2f(pv[j]);
  for (int p = 1; p < P; ++p) {
    uint4 w = *(const uint4*)(base + (size_t)p * n + (size_t)i * 8);
    const u16* pw = (const u16*)&w;
#pragma unroll
    for (int j = 0; j < 8; ++j) s[j] += bf2f(pw[j]);
  }
  uint4 os, og;
  u16* ps = (u16*)&os;
  u16* pg = (u16*)&og;
#pragma unroll
  for (int j = 0; j < 8; ++j) {
    ps[j] = f2bf(s[j]);
    pg[j] = f2bf(geluf(s[j]));
  }
  ((uint4*)qkvs)[i] = os;
  ((uint4*)gout)[i] = og;
}

// sum P bf16 partials (8 elems/thread) -> f32 out
__global__ __launch_bounds__(256) void reduce_add_bf16(const u16* __restrict__ base,
                                                       int P, int n8,
                                                       float* __restrict__ dst) {
  int i = blockIdx.x * 256 + threadIdx.x;
  if (i >= n8) return;
  size_t n = (size_t)n8 * 8;
  float s[8];
  uint4 v = ((const uint4*)base)[i];
  const u16* pv = (const u16*)&v;
#pragma unroll
  for (int j = 0; j < 8; ++j) s[j] = bf2f(pv[j]);
  for (int p = 1; p < P; ++p) {
    uint4 w = *(const uint4*)(base + (size_t)p * n + (size_t)i * 8);
    const u16* pw = (const u16*)&w;
#pragma unroll
    for (int j = 0; j < 8; ++j) s[j] += bf2f(pw[j]);
  }
  float4 o0 = {s[0], s[1], s[2], s[3]}, o1 = {s[4], s[5], s[6], s[7]};
  ((float4*)dst)[2 * i] = o0;
  ((float4*)dst)[2 * i + 1] = o1;
}

// ---------------- prep: tok split-K reduce + tanh + tau + RoPE + layouts --------------
// reduce_tanh fused in: lanes 0-31 sum the Pt tokPart partials for this s directly
// (2KB/block) and apply tanh + tau_pos. Saves a kernel launch + tokq/tokv round-trip.
// qkvs is the bf16 qkv sum. Q pre-scaled by 0.125*log2(e) for exp2-domain softmax.
#define QSCALE 0.18033688011112042f
__global__ __launch_bounds__(256) void prep_qkv(const u16* __restrict__ qkvs,
                                                const float* __restrict__ tokPart,
                                                int Pt,
                                                const float* __restrict__ alpha,
                                                const float* __restrict__ cosb,
                                                const float* __restrict__ sinb,
                                                const int* __restrict__ pos_ids,
                                                u16* __restrict__ Qb,
                                                u16* __restrict__ Kb,
                                                u16* __restrict__ Vt,
                                                u16* __restrict__ Vb) {
  const int s = blockIdx.x;
  const int tid = threadIdx.x;
  __shared__ float cs[16], sn[16], tq_s[32], tv_s[32];
  if (tid < 16) { cs[tid] = cosb[s * 16 + tid]; sn[tid] = sinb[s * 16 + tid]; }
  if (tid < 32) {
    float vq = 0.f, vv = 0.f;
    for (int p = 0; p < Pt; ++p) {
      const float* tp = tokPart + (size_t)p * (2048 * 64) + s * 64;
      vq += tp[tid];
      vv += tp[tid + 32];
    }
    float pos = (float)pos_ids[s] + 1.0f;
    float sig = 1.0f / (1.0f + __expf(-alpha[tid] * logf(pos)));
    float taupos = 0.5f + sig;
    tq_s[tid] = (tanhf(vq) + taupos) * QSCALE;
    tv_s[tid] = tanhf(vv) + taupos;
  }
  __syncthreads();
  const u16* row = qkvs + (size_t)s * 3072;

  if (Vb) {  // vectorized path (big ws): 384 8-wide units over 256 threads
    for (int u = tid; u < 384; u += 256) {
      if (u < 256) {  // Q: h = u>>3, dblk = u&7
        int h = u >> 3, dblk = u & 7;
        float tq = tq_s[h];
        float o[8];
        if (dblk < 4) {
          int i0 = dblk * 4;
          float xr[4], xi[4];
          ld4bf(row + h * 64 + i0, xr);
          ld4bf(row + h * 64 + 16 + i0, xi);
#pragma unroll
          for (int j = 0; j < 4; ++j) {
            float a = xr[j] * tq, b = xi[j] * tq;
            o[2 * j]     = a * cs[i0 + j] - b * sn[i0 + j];
            o[2 * j + 1] = a * sn[i0 + j] + b * cs[i0 + j];
          }
        } else {
          float x[8];
          ld8bf(row + h * 64 + dblk * 8, x);
#pragma unroll
          for (int j = 0; j < 8; ++j) o[j] = x[j] * tq;
        }
        *(uint4*)(Qb + ((size_t)h * 2048 + s) * 64 + dblk * 8) = pack8(o);
      } else if (u < 320) {  // K
        int u2 = u - 256;
        int h = u2 >> 3, dblk = u2 & 7;
        const u16* kr = row + 2048;
        float o[8];
        if (dblk < 4) {
          int i0 = dblk * 4;
          float xr[4], xi[4];
          ld4bf(kr + h * 64 + i0, xr);
          ld4bf(kr + h * 64 + 16 + i0, xi);
#pragma unroll
          for (int j = 0; j < 4; ++j) {
            o[2 * j]     = xr[j] * cs[i0 + j] - xi[j] * sn[i0 + j];
            o[2 * j + 1] = xr[j] * sn[i0 + j] + xi[j] * cs[i0 + j];
          }
        } else {
          float x[8];
          ld8bf(kr + h * 64 + dblk * 8, x);
#pragma unroll
          for (int j = 0; j < 8; ++j) o[j] = x[j];
        }
        *(uint4*)(Kb + ((size_t)h * 2048 + s) * 64 + dblk * 8) = pack8(o);
      } else {  // V -> Vb (vtrans handles Vt)
        int u2 = u - 320;
        int h = u2 >> 3, dblk = u2 & 7;
        float tv = tv_s[h];
        float x[8], o[8];
        ld8bf(row + 2560 + h * 64 + dblk * 8, x);
#pragma unroll
        for (int j = 0; j < 8; ++j) o[j] = x[j] * tv;
        *(uint4*)(Vb + ((size_t)h * 2048 + s) * 64 + dblk * 8) = pack8(o);
      }
    }
    return;
  }

  // scalar fallback (small ws): writes Vt directly
  for (int idx = tid; idx < 2048; idx += 256) {
    int h = idx >> 6, d = idx & 63;
    float tq = tq_s[h];
    float v;
    if (d < 32) {
      int i = d >> 1;
      float xr = bf2f(row[h * 64 + i]) * tq, xi = bf2f(row[h * 64 + 16 + i]) * tq;
      v = (d & 1) ? (xr * sn[i] + xi * cs[i]) : (xr * cs[i] - xi * sn[i]);
    } else v = bf2f(row[h * 64 + d]) * tq;
    Qb[((size_t)h * 2048 + s) * 64 + d] = f2bf(v);
  }
  for (int idx = tid; idx < 512; idx += 256) {
    int h = idx >> 6, d = idx & 63;
    const u16* kr = row + 2048;
    float v;
    if (d < 32) {
      int i = d >> 1;
      float xr = bf2f(kr[h * 64 + i]), xi = bf2f(kr[h * 64 + 16 + i]);
      v = (d & 1) ? (xr * sn[i] + xi * cs[i]) : (xr * cs[i] - xi * sn[i]);
    } else v = bf2f(kr[h * 64 + d]);
    Kb[((size_t)h * 2048 + s) * 64 + d] = f2bf(v);
  }
  for (int idx = tid; idx < 512; idx += 256) {
    int h = idx >> 6, d = idx & 63;
    float v = bf2f(row[2560 + h * 64 + d]) * tv_s[h];
    Vt[((size_t)h * 64 + d) * 2048 + s] = f2bf(v);
  }
}

// ---------------- bf16 transpose Vb[h][s][d] -> Vt[h][d][s] ----------------
__global__ __launch_bounds__(256) void vtrans(const u16* __restrict__ Vb,
                                              u16* __restrict__ Vt) {
  __shared__ u16 t[64][68];
  const int s0 = blockIdx.x * 64, h = blockIdx.y;
  const int tid = threadIdx.x;
  const u16* src = Vb + ((size_t)h * 2048 + s0) * 64;
#pragma unroll
  for (int p = 0; p < 4; ++p) {
    int v = p * 256 + tid;
    int r = v >> 4, c = (v & 15) * 4;
    uint2 w = *(const uint2*)(src + (size_t)r * 64 + c);
    t[r][c] = (u16)(w.x & 0xffff); t[r][c + 1] = (u16)(w.x >> 16);
    t[r][c + 2] = (u16)(w.y & 0xffff); t[r][c + 3] = (u16)(w.y >> 16);
  }
  __syncthreads();
  u16* dst = Vt + (size_t)h * 64 * 2048 + s0;
#pragma unroll
  for (int p = 0; p < 4; ++p) {
    int v = p * 256 + tid;
    int d = v >> 4, s = (v & 15) * 4;
    uint2 w;
    w.x = (u32)t[s][d] | ((u32)t[s + 1][d] << 16);
    w.y = (u32)t[s + 2][d] | ((u32)t[s + 3][d] << 16);
    *(uint2*)(dst + (size_t)d * 2048 + s) = w;
  }
}

// ---------------- flash attention (r5/v10 body: best-measured 43.2us) ----------------
// Double-buffered, one __syncthreads per tile, 16x16x16 PV with in-lane P frags,
// XCD pinning (all 51 chunks of a head share bid%8), LDS-staged coalesced epilogue.
__global__ __launch_bounds__(256, 4) void flash_attn(const u16* __restrict__ Qb,
                                                     const u16* __restrict__ Kb,
                                                     const u16* __restrict__ Vt,
                                                     u16* __restrict__ Opart,
                                                     float* __restrict__ ml) {
  __shared__ __attribute__((aligned(16))) u16 KsB[2][4096];
  __shared__ __attribute__((aligned(16))) u16 VsB[2][4096];
  const int bid = blockIdx.x;
  const int h = (bid & 7) | (((bid >> 3) & 3) << 3);  // head: bid%8 fixed per head -> one XCD
  const int e = 50 - (bid >> 5);                      // reversed: heaviest (qb=15) first
  const int kvh = h >> 2;
  // decode e -> (qb, cc): group a (a=0..5) holds qb=3a..3a+2, each with a+1 chunks of 6
  int a = 0;
  while (3 * (a + 1) * (a + 2) / 2 <= e) ++a;
  const int rem = e - 3 * a * (a + 1) / 2;
  const int qb = 3 * a + rem / (a + 1);
  const int cc = rem % (a + 1);
  const int k0 = cc * 6;
  const int kvTend = 2 * qb + 2;
  const int k1 = (k0 + 6 < kvTend) ? (k0 + 6) : kvTend;
  const int pid = h * 51 + e;

  const int tid = threadIdx.x, wid = tid >> 6, lane = tid & 63;
  const int l16 = lane & 15, quad = lane >> 4;
  const int lrow = lane >> 3, swz = (lane & 7) ^ lrow, sx = l16 & 7;

  const int q0 = qb * 128 + wid * 32;
  bf16x8 qf[2][2];
#pragma unroll
  for (int mt = 0; mt < 2; ++mt)
#pragma unroll
    for (int ks = 0; ks < 2; ++ks)
      qf[mt][ks] = *(const bf16x8*)(Qb + ((size_t)h * 2048 + q0 + mt * 16 + l16) * 64 +
                                    ks * 32 + quad * 8);

  f32x4 oacc[2][4] = {};          // O^T frags: [q-half][d-frag], lane q = l16
  float mrun[2] = {-3e38f, -3e38f};
  float lrun[2] = {0.f, 0.f};     // per-lane partial (reduced in epilogue)

  const u16* kgb = Kb + ((size_t)kvh * 2048) * 64;
  const u16* vgb = Vt + (size_t)kvh * 64 * 2048;

#define FA_STAGE(KT, BUF)                                                         \
  {                                                                               \
    const u16* kg_ = kgb + (size_t)(KT)*64 * 64;                                  \
    const u16* vg_ = vgb + (size_t)(KT)*64;                                       \
    _Pragma("unroll") for (int j = 0; j < 2; ++j) {                               \
      int i_ = wid * 2 + j;                                                       \
      gl_lds16(kg_ + (size_t)(i_ * 8 + lrow) * 64 + swz * 8, &KsB[BUF][i_ * 512]);\
      gl_lds16(vg_ + (size_t)(i_ * 8 + lrow) * 2048 + swz * 8, &VsB[BUF][i_ * 512]);\
    }                                                                             \
  }

  FA_STAGE(k0, 0)
  for (int kt = k0; kt < k1; ++kt) {
    const int cur = (kt - k0) & 1;
    __syncthreads();
    if (kt + 1 < k1) FA_STAGE(kt + 1, cur ^ 1)
    const u16* Ks = KsB[cur];
    const u16* Vs = VsB[cur];

    // S^T = K Q^T : sacc[mt][kf], C row = k (quad*4+r+16kf), col = q (l16)
    f32x4 sacc[2][4] = {};
    __builtin_amdgcn_s_setprio(1);
#pragma unroll
    for (int kf = 0; kf < 4; ++kf) {
      bf16x8 a0 = *(const bf16x8*)(Ks + (kf * 16 + l16) * 64 + ((quad ^ sx) << 3));
      bf16x8 a1 = *(const bf16x8*)(Ks + (kf * 16 + l16) * 64 + (((4 + quad) ^ sx) << 3));
      sacc[0][kf] = __builtin_amdgcn_mfma_f32_16x16x32_bf16(a0, qf[0][0], sacc[0][kf], 0, 0, 0);
      sacc[0][kf] = __builtin_amdgcn_mfma_f32_16x16x32_bf16(a1, qf[0][1], sacc[0][kf], 0, 0, 0);
      sacc[1][kf] = __builtin_amdgcn_mfma_f32_16x16x32_bf16(a0, qf[1][0], sacc[1][kf], 0, 0, 0);
      sacc[1][kf] = __builtin_amdgcn_mfma_f32_16x16x32_bf16(a1, qf[1][1], sacc[1][kf], 0, 0, 0);
    }
    __builtin_amdgcn_s_setprio(0);

    const bool msk = (kt >= 2 * qb);  // diagonal tiles only
    s16x4 pb[2][4];                   // PV B-frags, built in-lane (no redistribution)
#pragma unroll
    for (int mt = 0; mt < 2; ++mt) {
      const int qg = q0 + mt * 16 + l16;       // this lane's q (fixed)
      if (msk) {
        const int kb = kt * 64 + quad * 4;
#pragma unroll
        for (int kf = 0; kf < 4; ++kf)
#pragma unroll
          for (int r = 0; r < 4; ++r)
            if (kb + kf * 16 + r > qg) sacc[mt][kf][r] = -1e9f;
      }
      f32x4 m4 = sacc[mt][0];
      m4 = __builtin_elementwise_max(m4, sacc[mt][1]);
      m4 = __builtin_elementwise_max(m4, sacc[mt][2]);
      m4 = __builtin_elementwise_max(m4, sacc[mt][3]);
      float mx = fmaxf(fmaxf(m4[0], m4[1]), fmaxf(m4[2], m4[3]));
      mx = fmaxf(mx, __shfl_xor(mx, 16));
      mx = fmaxf(mx, __shfl_xor(mx, 32));
      float mn = fmaxf(mrun[mt], mx);
      float al = __builtin_amdgcn_exp2f(mrun[mt] - mn);
      mrun[mt] = mn;
      float psl = 0.f;
#pragma unroll
      for (int kf = 0; kf < 4; ++kf) {
        bf16x4 ph;
#pragma unroll
        for (int r = 0; r < 4; ++r) {
          float p = __builtin_amdgcn_exp2f(sacc[mt][kf][r] - mn);
          psl += p;
          ph[r] = (__bf16)p;
        }
        union { bf16x4 h; s16x4 s; } cv;
        cv.h = ph;
        pb[mt][kf] = cv.s;
      }
      lrun[mt] = lrun[mt] * al + psl;
#pragma unroll
      for (int df = 0; df < 4; ++df) oacc[mt][df] *= al;
    }

    // O^T += V^T P : A = Vs[d][k] (b64 frags), B = in-lane P frags (16x16x16)
    __builtin_amdgcn_s_setprio(1);
#pragma unroll
    for (int kf = 0; kf < 4; ++kf) {
#pragma unroll
      for (int df = 0; df < 4; ++df) {
        s16x4 va = *(const s16x4*)(Vs + (df * 16 + l16) * 64 +
                                   (((kf * 2 + (quad >> 1)) ^ sx) << 3) + ((quad & 1) << 2));
        oacc[0][df] = mfma_16x16x16_bf16(va, pb[0][kf], oacc[0][df]);
        oacc[1][df] = mfma_16x16x16_bf16(va, pb[1][kf], oacc[1][df]);
      }
    }
    __builtin_amdgcn_s_setprio(0);
  }
#undef FA_STAGE

  // epilogue: reduce lrun; stage bf16 O in LDS (XOR-swizzled 16B granules), then
  // fully-coalesced 16B/lane global writes. KsB (16KB) exactly holds 128x64 bf16.
  __syncthreads();                     // all waves done reading KsB
  char* Ls = (char*)KsB;
#pragma unroll
  for (int mt = 0; mt < 2; ++mt) {
    float lt = lrun[mt];
    lt += __shfl_xor(lt, 16);
    lt += __shfl_xor(lt, 32);
    const int qrow = wid * 32 + mt * 16 + l16;
#pragma unroll
    for (int df = 0; df < 4; ++df) {
      uint2 pk2;
      pk2.x = (u32)f2bf(oacc[mt][df][0]) | ((u32)f2bf(oacc[mt][df][1]) << 16);
      pk2.y = (u32)f2bf(oacc[mt][df][2]) | ((u32)f2bf(oacc[mt][df][3]) << 16);
      int boff = qrow * 128 + ((df * 32 + quad * 8) ^ ((qrow & 7) << 4));
      *(uint2*)(Ls + boff) = pk2;
    }
    if (quad == 0) {
      ml[((size_t)pid * 128 + qrow) * 2] = mrun[mt];
      ml[((size_t)pid * 128 + qrow) * 2 + 1] = lt;
    }
  }
  __syncthreads();
  char* Op = (char*)(Opart + (size_t)pid * 128 * 64);
#pragma unroll
  for (int p = 0; p < 4; ++p) {
    int off = p * 4096 + tid * 16;
    int row = off >> 7, wb = off & 127;
    uint4 v = *(const uint4*)(Ls + row * 128 + (wb ^ ((row & 7) << 4)));
    *(uint4*)(Op + off) = v;
  }
}

// ---------------- combine partials: O = sum(w_c O_c) / sum(w_c l_c) ----------------
__global__ __launch_bounds__(256) void fa_combine(const u16* __restrict__ Opart,
                                                  const float* __restrict__ ml,
                                                  u16* __restrict__ Ob) {
  const int qb = blockIdx.x, h = blockIdx.y;
  const int C = (2 * qb + 7) / 6;                  // chunks for this qb (size-6 chunks)
  const int aa = qb / 3, bb = qb % 3;
  const int base = h * 51 + 3 * aa * (aa + 1) / 2 + bb * (aa + 1);
  const int t = threadIdx.x;
#pragma unroll
  for (int u = 0; u < 8; ++u) {
    int unit = u * 256 + t;
    int row = unit >> 4, d4 = unit & 15;
    float mstar = -3e38f;
    for (int c = 0; c < C; ++c)
      mstar = fmaxf(mstar, ml[((size_t)(base + c) * 128 + row) * 2]);
    float4 o = {0.f, 0.f, 0.f, 0.f};
    float lsum = 0.f;
    for (int c = 0; c < C; ++c) {
      const float* mlp = &ml[((size_t)(base + c) * 128 + row) * 2];
      float w = __builtin_amdgcn_exp2f(mlp[0] - mstar);
      uint2 v = *(const uint2*)(Opart + ((size_t)(base + c) * 128 + row) * 64 + d4 * 4);
      o.x += w * bf2f((u16)(v.x & 0xffff));
      o.y += w * bf2f((u16)(v.x >> 16));
      o.z += w * bf2f((u16)(v.y & 0xffff));
      o.w += w * bf2f((u16)(v.y >> 16));
      lsum += w * mlp[1];
    }
    float inv = 1.0f / lsum;
    uint2 pk;
    pk.x = (u32)f2bf(o.x * inv) | ((u32)f2bf(o.y * inv) << 16);
    pk.y = (u32)f2bf(o.z * inv) | ((u32)f2bf(o.w * inv) << 16);
    *(uint2*)(Ob + (size_t)(qb * 128 + row) * 2048 + h * 64 + d4 * 4) = pk;
  }
}

// ---------------- launcher ----------------
extern "C" void kernel_launch(void* const* d_in, const int* in_sizes, int n_in,
                              void* d_out, int out_size, void* d_ws, size_t ws_size,
                              hipStream_t stream) {
  (void)in_sizes; (void)n_in; (void)out_size;
  const float* hidden = (const float*)d_in[0];
  const float* cosb   = (const float*)d_in[1];
  const float* sinb   = (const float*)d_in[2];
  const int*   pos    = (const int*)d_in[3];
  const float* Wq     = (const float*)d_in[4];
  const float* Wk     = (const float*)d_in[5];
  const float* Wv     = (const float*)d_in[6];
  const float* Wo     = (const float*)d_in[7];
  const float* tWq    = (const float*)d_in[8];
  const float* tWv    = (const float*)d_in[9];
  const float* alpha  = (const float*)d_in[10];
  float* out = (float*)d_out;

  const bool big = ws_size >= (size_t)120 * 1024 * 1024;
  const int Pq = big ? 2 : 1;
  const int Pt = big ? 8 : 1;
  const int Po = big ? 2 : 1;

  char* ws = (char*)d_ws;
  size_t off = 0;
  auto alloc = [&](size_t bytes) -> void* {
    void* p = ws + off;
    off += (bytes + 255) & ~(size_t)255;
    return p;
  };
  u16*   WoT   = (u16*)alloc(2048ull * 2048 * 2);
  u16*   Tt    = (u16*)alloc(64ull * 3072 * 2);
  u16*   Qb    = (u16*)alloc(32ull * 2048 * 64 * 2);
  u16*   Kb    = (u16*)alloc(8ull * 2048 * 64 * 2);
  u16*   Vt    = (u16*)alloc(8ull * 64 * 2048 * 2);
  u16*   Ob    = (u16*)alloc(2048ull * 2048 * 2);
  u16*   featb = (u16*)alloc(2048ull * 3072 * 2);
  u16*   Vb    = big ? (u16*)alloc(8ull * 2048 * 64 * 2) : nullptr;
  // early region (dead after prep) -> reused for flash partials -> out partials
  size_t E = off;
  u16*   Xb       = (u16*)alloc(2048ull * 2048 * 2);
  u16*   WqkvT    = (u16*)alloc(3072ull * 2048 * 2);
  u16*   qkvPartB = (u16*)alloc((size_t)Pq * 2048 * 3072 * 2);
  u16*   qkvs     = (u16*)alloc(2048ull * 3072 * 2);
  float* tokPart = (float*)(ws + E);
  u16*   Opart   = (u16*)(ws + E);                             // 1632*128*64*2 = 26.7 MB
  float* mlbuf   = (float*)(ws + E + 1632ull * 128 * 64 * 2);  // +1.7 MB
  u16*   outPart = (u16*)(ws + E);                             // Po*2048*2048*2 = 16.8 MB

  transpose_all<<<4704, 256, 0, stream>>>(Wq, Wk, Wv, Wo, tWq, tWv, WqkvT, WoT, Tt,
                                          hidden, Xb);

  gemm_bt<2, 2, true><<<dim3(24, 16, Pq), 256, 0, stream>>>(
      Xb, WqkvT, qkvPartB, 2048, 3072, 2048, (32 + Pq - 1) / Pq);
  reduce_gelu_b<<<3072, 256, 0, stream>>>(qkvPartB, Pq, 2048 * 3072 / 8, qkvs, featb);

  gemm_bt<4, 1, false><<<dim3(1, 8, Pt), 256, 0, stream>>>(
      featb, Tt, tokPart, 2048, 64, 3072, (48 + Pt - 1) / Pt);

  prep_qkv<<<2048, 256, 0, stream>>>(qkvs, tokPart, Pt, alpha, cosb, sinb, pos,
                                     Qb, Kb, Vt, Vb);
  if (big) vtrans<<<dim3(32, 8), 256, 0, stream>>>(Vb, Vt);

  flash_attn<<<1632, 256, 0, stream>>>(Qb, Kb, Vt, Opart, mlbuf);
  fa_combine<<<dim3(16, 32), 256, 0, stream>>>(Opart, mlbuf, Ob);

  gemm_bt<2, 2, true><<<dim3(16, 16, Po), 256, 0, stream>>>(
      Ob, WoT, outPart, 2048, 2048, 2048, (32 + Po - 1) / Po);
  reduce_add_bf16<<<2048, 256, 0, stream>>>(outPart, Po, 2048 * 2048 / 8, out);
}